// Round 9
// baseline (116.072 us; speedup 1.0000x reference)
//
#include <hip/hip_runtime.h>

typedef unsigned int   u32;
typedef unsigned short u16;
typedef __bf16 bf16x8 __attribute__((ext_vector_type(8)));
typedef float  f32x4  __attribute__((ext_vector_type(4)));
typedef float  f32x16 __attribute__((ext_vector_type(16)));

__device__ __forceinline__ u16 f2b(float f) {
  u32 u = __float_as_uint(f);
  u = (u + 0x7fffu + ((u >> 16) & 1u)) >> 16;   // RNE
  return (u16)u;
}
__device__ __forceinline__ float b2f_lo(u32 u) { return __uint_as_float(u << 16); }
__device__ __forceinline__ float b2f_hi(u32 u) { return __uint_as_float(u & 0xffff0000u); }
__device__ __forceinline__ float silu_f(float x) { return __fdividef(x, 1.f + __expf(-x)); }

__device__ __forceinline__ float dot8(uint4 q, uint4 k, float acc) {
  acc += b2f_lo(q.x) * b2f_lo(k.x) + b2f_hi(q.x) * b2f_hi(k.x);
  acc += b2f_lo(q.y) * b2f_lo(k.y) + b2f_hi(q.y) * b2f_hi(k.y);
  acc += b2f_lo(q.z) * b2f_lo(k.z) + b2f_hi(q.z) * b2f_hi(k.z);
  acc += b2f_lo(q.w) * b2f_lo(k.w) + b2f_hi(q.w) * b2f_hi(k.w);
  return acc;
}

// ---------- prep: Wk/Wq (256x256 f32, [k][n]) -> bf16 [n][k]  (r4-exact) ----------
__global__ void prep_wt(const float* __restrict__ Wk, const float* __restrict__ Wq,
                        u16* __restrict__ Wkt, u16* __restrict__ Wqt) {
  for (int idx = blockIdx.x * 256 + threadIdx.x; idx < 256 * 256; idx += gridDim.x * 256) {
    int n = idx >> 8, k = idx & 255;
    Wkt[idx] = f2b(Wk[k * 256 + n]);
    Wqt[idx] = f2b(Wq[k * 256 + n]);
  }
}

// ---------- prep: MFMA A-frag tables + BT bias tables (r4-exact) ----------
__global__ void prep_mlpfrag(const float* __restrict__ W0, const float* __restrict__ W1,
                             const float* __restrict__ b0, const float* __restrict__ b1,
                             const float* __restrict__ W2,
                             u16* __restrict__ W0A, u16* __restrict__ W1A,
                             float* __restrict__ BT) {
  int t = threadIdx.x;            // 512 = 8 heads x 64 lanes
  int h = t >> 6, l = t & 63;
  int hf = l >> 5, j = l & 31;
  #pragma unroll
  for (int e = 0; e < 8; e++) {
    int k = 8 * hf + e;
    float v0 = (j < 16 && k < 10) ? W0[h * 160 + k * 16 + j] : 0.f;
    W0A[t * 8 + e] = f2b(v0);
    int jin = (k & 3) + 8 * ((k >> 2) & 1) + 4 * (k >> 3);  // sigma(k)
    float v1 = (j < 16) ? W1[h * 256 + jin * 16 + j] : 0.f;
    W1A[t * 8 + e] = f2b(v1);
    int cj = (e & 3) + 8 * (e >> 2) + 4 * hf;
    BT[t * 32 + e]      = b0[h * 16 + cj];
    BT[t * 32 + 8 + e]  = b1[h * 16 + cj];
    BT[t * 32 + 16 + e] = W2[h * 16 + cj];
  }
}

// ---------- GEMM: C_bf16[8192][256] = A_f32[8192][256] @ W + bias ----------
// Tile 64x128 (was 128x128): 512 blocks = 2/CU for latency hiding. 4 waves, wave-tile 32x64.
#define LDA 72
__global__ __launch_bounds__(256) void gemm_proj(
    const float* __restrict__ A0, const float* __restrict__ A1,
    const u16* __restrict__ B0, const u16* __restrict__ B1,
    const float* __restrict__ bias0, const float* __restrict__ bias1,
    u16* __restrict__ C0, u16* __restrict__ C1) {
  const float* A; const u16* Bt; const float* bias; u16* C;
  if (blockIdx.z == 0) { A = A0; Bt = B0; bias = bias0; C = C0; }
  else                 { A = A1; Bt = B1; bias = bias1; C = C1; }
  __shared__ __align__(16) u16 As[64 * LDA];
  __shared__ __align__(16) u16 Bs[128 * LDA];
  const int t = threadIdx.x;
  const int w = t >> 6, lane = t & 63;
  const int wm = w >> 1, wn = w & 1;
  const int row0 = blockIdx.x * 64, col0 = blockIdx.y * 128;
  f32x4 acc[2][4] = {};
  for (int kk = 0; kk < 256; kk += 64) {
    // stage A (f32 -> bf16): 64 rows x 64 k
    #pragma unroll
    for (int p = 0; p < 4; p++) {
      int r = p * 16 + (t >> 4), q = (t & 15) * 4;
      float4 v = *(const float4*)(A + (size_t)(row0 + r) * 256 + kk + q);
      uint2 pk;
      pk.x = (u32)f2b(v.x) | ((u32)f2b(v.y) << 16);
      pk.y = (u32)f2b(v.z) | ((u32)f2b(v.w) << 16);
      *(uint2*)(&As[r * LDA + q]) = pk;
    }
    // stage B (bf16): 128 cols x 64 k
    #pragma unroll
    for (int p = 0; p < 4; p++) {
      int r = p * 32 + (t >> 3), q = (t & 7) * 8;
      *(uint4*)(&Bs[r * LDA + q]) = *(const uint4*)(Bt + (size_t)(col0 + r) * 256 + kk + q);
    }
    __syncthreads();
    #pragma unroll
    for (int ks = 0; ks < 2; ks++) {
      bf16x8 af[2], bfr[4];
      #pragma unroll
      for (int i = 0; i < 2; i++)
        af[i]  = *(const bf16x8*)(&As[(wm * 32 + i * 16 + (lane & 15)) * LDA + ks * 32 + (lane >> 4) * 8]);
      #pragma unroll
      for (int j = 0; j < 4; j++)
        bfr[j] = *(const bf16x8*)(&Bs[(wn * 64 + j * 16 + (lane & 15)) * LDA + ks * 32 + (lane >> 4) * 8]);
      #pragma unroll
      for (int i = 0; i < 2; i++)
        #pragma unroll
        for (int j = 0; j < 4; j++)
          acc[i][j] = __builtin_amdgcn_mfma_f32_16x16x32_bf16(af[i], bfr[j], acc[i][j], 0, 0, 0);
    }
    __syncthreads();
  }
  // epilogue: +bias, cvt bf16, store. C/D: col=lane&15, row=4*(lane>>4)+q (m89)
  #pragma unroll
  for (int j = 0; j < 4; j++) {
    int c = col0 + wn * 64 + j * 16 + (lane & 15);
    float bv = bias[c];
    #pragma unroll
    for (int i = 0; i < 2; i++) {
      int r0 = row0 + wm * 32 + i * 16 + (lane >> 4) * 4;
      #pragma unroll
      for (int q = 0; q < 4; q++)
        C[(size_t)(r0 + q) * 256 + c] = f2b(acc[i][j][q] + bv);
    }
  }
}

// ---------- fused (r4-EXACT): gather+dot (VALU) + MLP (MFMA, swapped operands) ----------
// grid = B*N = 8192 blocks; block = 512 = 8 waves; wave = head; lane = (hf, m)
__global__ __launch_bounds__(512) void fused_main(
    const u16* __restrict__ Kbf, const u16* __restrict__ Qbf,
    const int* __restrict__ nidx, const float* __restrict__ g,
    const u16* __restrict__ W0A, const u16* __restrict__ W1A,
    const float* __restrict__ BT, const float* __restrict__ b2,
    float* __restrict__ out) {
  __shared__ float lout[256];
  const int t = threadIdx.x;
  const int h = t >> 6, lane = t & 63;
  const int hf = lane >> 5, m = lane & 31;
  const int bn = blockIdx.x;
  const int b = bn >> 12;
  const int row = bn * 32 + m;
  const int hs = __builtin_amdgcn_readfirstlane(h);

  // MFMA A-fragments + bias tables
  const bf16x8 a0 = *(const bf16x8*)(W0A + (size_t)(hs * 64 + lane) * 8);
  const bf16x8 a1 = *(const bf16x8*)(W1A + (size_t)(hs * 64 + lane) * 8);
  const float4* btp = (const float4*)(BT + (size_t)t * 32);
  const float4 t0 = btp[0], t1 = btp[1], t2 = btp[2], t3 = btp[3], t4 = btp[4], t5 = btp[5];
  const float bj0[8] = {t0.x, t0.y, t0.z, t0.w, t1.x, t1.y, t1.z, t1.w};
  const float bj1[8] = {t2.x, t2.y, t2.z, t2.w, t3.x, t3.y, t3.z, t3.w};
  const float wj[8]  = {t4.x, t4.y, t4.z, t4.w, t5.x, t5.y, t5.z, t5.w};
  const float b2s = b2[hs];

  // g B-fragment (lane supplies k-slots 8*hf+e)
  const float* gp = g + (size_t)row * 10;
  bf16x8 gf = {};
  {
    float2 v0 = *(const float2*)(gp + hf * 8);
    gf[0] = (__bf16)v0.x; gf[1] = (__bf16)v0.y;
    if (hf == 0) {
      float2 v1 = *(const float2*)(gp + 2);
      float2 v2 = *(const float2*)(gp + 4);
      float2 v3 = *(const float2*)(gp + 6);
      gf[2] = (__bf16)v1.x; gf[3] = (__bf16)v1.y;
      gf[4] = (__bf16)v2.x; gf[5] = (__bf16)v2.y;
      gf[6] = (__bf16)v3.x; gf[7] = (__bf16)v3.y;
    }
  }

  // feat dot (bf16 unpack + fp32 fma, d = hf*16 .. hf*16+15)
  const int kidx = nidx[row];
  const uint4* qp = (const uint4*)(Qbf + (size_t)bn * 256 + h * 32 + hf * 16);
  const uint4* kp = (const uint4*)(Kbf + ((size_t)b * 4096 + (size_t)kidx) * 256 + h * 32 + hf * 16);
  uint4 q0 = qp[0], q1 = qp[1], k0 = kp[0], k1 = kp[1];
  float dpart = dot8(q1, k1, dot8(q0, k0, 0.f));

  const f32x16 z = {};

  // layer 0
  f32x16 acc = __builtin_amdgcn_mfma_f32_32x32x16_bf16(a0, gf, z, 0, 0, 0);
  bf16x8 h0b;
  #pragma unroll
  for (int e = 0; e < 8; e++) h0b[e] = (__bf16)silu_f(acc[e] + bj0[e]);

  // layer 1 + W2 contraction
  acc = __builtin_amdgcn_mfma_f32_32x32x16_bf16(a1, h0b, z, 0, 0, 0);
  float part = 0.f;
  #pragma unroll
  for (int e = 0; e < 8; e++) part += silu_f(acc[e] + bj1[e]) * wj[e];

  // cross-half combine + final
  float osum = part + __shfl_xor(part, 32, 64);
  float feat = (dpart + __shfl_xor(dpart, 32, 64)) * 0.17677669529663687f;
  float res = feat + silu_f(osum + b2s);

  if (hf == 0) lout[m * 8 + h] = res;
  __syncthreads();
  if (t < 64) {
    float4 v = ((const float4*)lout)[t];
    ((float4*)(out + (size_t)bn * 256))[t] = v;
  }
}

extern "C" void kernel_launch(void* const* d_in, const int* in_sizes, int n_in,
                              void* d_out, int out_size, void* d_ws, size_t ws_size,
                              hipStream_t stream) {
  const float* g_in = (const float*)d_in[0];
  // d_in[1] = nbhd_mask: unused by the reference
  const float* kf   = (const float*)d_in[2];
  const float* qf   = (const float*)d_in[3];
  const int*   idx  = (const int*)d_in[4];
  const float* Wk   = (const float*)d_in[5];
  const float* bk   = (const float*)d_in[6];
  const float* Wq   = (const float*)d_in[7];
  const float* bq   = (const float*)d_in[8];
  const float* W0   = (const float*)d_in[9];
  const float* b0   = (const float*)d_in[10];
  const float* W1   = (const float*)d_in[11];
  const float* b1   = (const float*)d_in[12];
  const float* W2   = (const float*)d_in[13];
  const float* b2   = (const float*)d_in[14];

  char* ws = (char*)d_ws;
  u16*   Kbf = (u16*)ws;                                        // 4 MB
  u16*   Qbf = (u16*)(ws + 4u * 1024 * 1024);                   // 4 MB
  u16*   Wkt = (u16*)(ws + 8u * 1024 * 1024);                   // 128 KB
  u16*   Wqt = (u16*)(ws + 8u * 1024 * 1024 + 131072);          // 128 KB
  u16*   W0A = (u16*)(ws + 8u * 1024 * 1024 + 262144);          // 8 KB
  u16*   W1A = (u16*)(ws + 8u * 1024 * 1024 + 262144 + 8192);   // 8 KB
  float* BT  = (float*)(ws + 8u * 1024 * 1024 + 262144 + 16384);// 64 KB

  prep_wt<<<64, 256, 0, stream>>>(Wk, Wq, Wkt, Wqt);
  prep_mlpfrag<<<1, 512, 0, stream>>>(W0, W1, b0, b1, W2, W0A, W1A, BT);
  gemm_proj<<<dim3(128, 2, 2), 256, 0, stream>>>(kf, qf, Wkt, Wqt, bk, bq, Kbf, Qbf);
  fused_main<<<8192, 512, 0, stream>>>(Kbf, Qbf, idx, g_in, W0A, W1A, BT, b2,
                                       (float*)d_out);
}

// Round 10
// 63.753 us; speedup vs baseline: 1.8206x; 1.8206x over previous
//
#include <hip/hip_runtime.h>

typedef unsigned int   u32;
typedef unsigned short u16;
typedef __bf16 bf16x8 __attribute__((ext_vector_type(8)));
typedef float  f32x4  __attribute__((ext_vector_type(4)));
typedef float  f32x16 __attribute__((ext_vector_type(16)));

__device__ __forceinline__ u16 f2b(float f) {
  u32 u = __float_as_uint(f);
  u = (u + 0x7fffu + ((u >> 16) & 1u)) >> 16;   // RNE
  return (u16)u;
}
__device__ __forceinline__ float silu_f(float x) { return __fdividef(x, 1.f + __expf(-x)); }

// ---------- prep (single launch, 1089 blocks x 512):
//   blocks 0..1023  : pack g -> G2 B-fragments (bf16x8 per (bn,lane)), 8 bn per block
//   blocks 1024..1087: transpose Wk/Wq [k][n] -> bf16 [n][k]
//   block  1088      : MLP A-frag tables (W0A/W1A, sigma-permuted W1) + BT2 bias table
__global__ __launch_bounds__(512) void prep_all(
    const float* __restrict__ g,
    const float* __restrict__ Wk, const float* __restrict__ Wq,
    const float* __restrict__ W0, const float* __restrict__ W1,
    const float* __restrict__ b0, const float* __restrict__ b1,
    const float* __restrict__ W2,
    u16* __restrict__ Wkt, u16* __restrict__ Wqt,
    u16* __restrict__ W0A, u16* __restrict__ W1A,
    float* __restrict__ BT2, u16* __restrict__ G2, int useG2) {
  const int blk = blockIdx.x, t = threadIdx.x;
  if (blk < 1024) {
    if (!useG2) return;
    const int sub = t >> 6, lane = t & 63;
    const int hf = lane >> 5, m = lane & 31;
    const int bn = blk * 8 + sub;
    const float* gp = g + ((size_t)bn * 32 + m) * 10;
    bf16x8 gf = {};
    float2 v0 = *(const float2*)(gp + hf * 8);
    gf[0] = (__bf16)v0.x; gf[1] = (__bf16)v0.y;
    if (hf == 0) {
      float2 v1 = *(const float2*)(gp + 2);
      float2 v2 = *(const float2*)(gp + 4);
      float2 v3 = *(const float2*)(gp + 6);
      gf[2] = (__bf16)v1.x; gf[3] = (__bf16)v1.y;
      gf[4] = (__bf16)v2.x; gf[5] = (__bf16)v2.y;
      gf[6] = (__bf16)v3.x; gf[7] = (__bf16)v3.y;
    }
    *(bf16x8*)(G2 + ((size_t)bn * 64 + lane) * 8) = gf;
  } else if (blk < 1088) {
    for (int idx = (blk - 1024) * 512 + t; idx < 65536; idx += 64 * 512) {
      int n = idx >> 8, k = idx & 255;
      Wkt[idx] = f2b(Wk[k * 256 + n]);
      Wqt[idx] = f2b(Wq[k * 256 + n]);
    }
  } else {
    const int h = t >> 6, l = t & 63;
    const int hf = l >> 5, j = l & 31;
    float vals[24];
    #pragma unroll
    for (int e = 0; e < 8; e++) {
      int k = 8 * hf + e;
      float v0 = (j < 16 && k < 10) ? W0[h * 160 + k * 16 + j] : 0.f;
      W0A[t * 8 + e] = f2b(v0);
      int jin = (k & 3) + 8 * ((k >> 2) & 1) + 4 * (k >> 3);  // sigma(k)
      float v1 = (j < 16) ? W1[h * 256 + jin * 16 + j] : 0.f;
      W1A[t * 8 + e] = f2b(v1);
      int cj = (e & 3) + 8 * (e >> 2) + 4 * hf;
      vals[e]      = b0[h * 16 + cj];
      vals[8 + e]  = b1[h * 16 + cj];
      vals[16 + e] = W2[h * 16 + cj];
    }
    #pragma unroll
    for (int j4 = 0; j4 < 6; j4++)
      ((float4*)BT2)[j4 * 512 + t] =
        make_float4(vals[4 * j4], vals[4 * j4 + 1], vals[4 * j4 + 2], vals[4 * j4 + 3]);
  }
}

// ---------- GEMM: C_bf16[8192][256] = A_f32[8192][256] @ W + bias (r4-verified, 128x128) ----------
#define LDA 72
__global__ __launch_bounds__(256) void gemm_proj(
    const float* __restrict__ A0, const float* __restrict__ A1,
    const u16* __restrict__ B0, const u16* __restrict__ B1,
    const float* __restrict__ bias0, const float* __restrict__ bias1,
    u16* __restrict__ C0, u16* __restrict__ C1) {
  const float* A; const u16* Bt; const float* bias; u16* C;
  if (blockIdx.z == 0) { A = A0; Bt = B0; bias = bias0; C = C0; }
  else                 { A = A1; Bt = B1; bias = bias1; C = C1; }
  __shared__ __align__(16) u16 As[128 * LDA];
  __shared__ __align__(16) u16 Bs[128 * LDA];
  const int t = threadIdx.x;
  const int w = t >> 6, lane = t & 63;
  const int wm = w >> 1, wn = w & 1;
  const int row0 = blockIdx.x * 128, col0 = blockIdx.y * 128;
  f32x4 acc[4][4] = {};
  for (int kk = 0; kk < 256; kk += 64) {
    #pragma unroll
    for (int p = 0; p < 8; p++) {
      int r = p * 16 + (t >> 4), q = (t & 15) * 4;
      float4 v = *(const float4*)(A + (size_t)(row0 + r) * 256 + kk + q);
      uint2 pk;
      pk.x = (u32)f2b(v.x) | ((u32)f2b(v.y) << 16);
      pk.y = (u32)f2b(v.z) | ((u32)f2b(v.w) << 16);
      *(uint2*)(&As[r * LDA + q]) = pk;
    }
    #pragma unroll
    for (int p = 0; p < 4; p++) {
      int r = p * 32 + (t >> 3), q = (t & 7) * 8;
      *(uint4*)(&Bs[r * LDA + q]) = *(const uint4*)(Bt + (size_t)(col0 + r) * 256 + kk + q);
    }
    __syncthreads();
    #pragma unroll
    for (int ks = 0; ks < 2; ks++) {
      bf16x8 af[4], bfr[4];
      #pragma unroll
      for (int i = 0; i < 4; i++) {
        af[i]  = *(const bf16x8*)(&As[(wm * 64 + i * 16 + (lane & 15)) * LDA + ks * 32 + (lane >> 4) * 8]);
        bfr[i] = *(const bf16x8*)(&Bs[(wn * 64 + i * 16 + (lane & 15)) * LDA + ks * 32 + (lane >> 4) * 8]);
      }
      #pragma unroll
      for (int i = 0; i < 4; i++)
        #pragma unroll
        for (int j = 0; j < 4; j++)
          acc[i][j] = __builtin_amdgcn_mfma_f32_16x16x32_bf16(af[i], bfr[j], acc[i][j], 0, 0, 0);
    }
    __syncthreads();
  }
  #pragma unroll
  for (int j = 0; j < 4; j++) {
    int c = col0 + wn * 64 + j * 16 + (lane & 15);
    float bv = bias[c];
    #pragma unroll
    for (int i = 0; i < 4; i++) {
      int r0 = row0 + wm * 64 + i * 16 + (lane >> 4) * 4;
      #pragma unroll
      for (int q = 0; q < 4; q++)
        C[(size_t)(r0 + q) * 256 + c] = f2b(acc[i][j][q] + bv);
    }
  }
}

// ---------- fused v7: MFMA feat-dot + MFMA MLP; coalesced tables ----------
// grid = B*N = 8192; block = 512 = 8 waves; wave = head; lane = (hf, m)
template<int USE_G2>
__global__ __launch_bounds__(512) void fused_main(
    const u16* __restrict__ Kbf, const u16* __restrict__ Qbf,
    const int* __restrict__ nidx, const float* __restrict__ g,
    const u16* __restrict__ W0A, const u16* __restrict__ W1A,
    const float* __restrict__ BT2, const float* __restrict__ b2,
    const u16* __restrict__ G2, float* __restrict__ out) {
  __shared__ float lout[256];
  const int t = threadIdx.x;
  const int h = t >> 6, lane = t & 63;
  const int hf = lane >> 5, m = lane & 31;
  const int bn = blockIdx.x;
  const int b = bn >> 12;
  const int row = bn * 32 + m;
  const int hs = __builtin_amdgcn_readfirstlane(h);

  // MLP A-fragments (coalesced) + bias tables (coalesced, column-major BT2)
  const bf16x8 a0 = *(const bf16x8*)(W0A + (size_t)(hs * 64 + lane) * 8);
  const bf16x8 a1 = *(const bf16x8*)(W1A + (size_t)(hs * 64 + lane) * 8);
  const float4* bt = (const float4*)BT2;
  const float4 t0 = bt[0 * 512 + t], t1 = bt[1 * 512 + t], t2 = bt[2 * 512 + t];
  const float4 t3 = bt[3 * 512 + t], t4 = bt[4 * 512 + t], t5 = bt[5 * 512 + t];
  const float bj0[8] = {t0.x, t0.y, t0.z, t0.w, t1.x, t1.y, t1.z, t1.w};
  const float bj1[8] = {t2.x, t2.y, t2.z, t2.w, t3.x, t3.y, t3.z, t3.w};
  const float wj[8]  = {t4.x, t4.y, t4.z, t4.w, t5.x, t5.y, t5.z, t5.w};
  const float b2s = b2[hs];

  // g B-fragment
  bf16x8 gf;
  if (USE_G2) {
    gf = *(const bf16x8*)(G2 + ((size_t)bn * 64 + lane) * 8);
  } else {
    bf16x8 gt = {};
    const float* gp = g + (size_t)row * 10;
    float2 v0 = *(const float2*)(gp + hf * 8);
    gt[0] = (__bf16)v0.x; gt[1] = (__bf16)v0.y;
    if (hf == 0) {
      float2 v1 = *(const float2*)(gp + 2);
      float2 v2 = *(const float2*)(gp + 4);
      float2 v3 = *(const float2*)(gp + 6);
      gt[2] = (__bf16)v1.x; gt[3] = (__bf16)v1.y;
      gt[4] = (__bf16)v2.x; gt[5] = (__bf16)v2.y;
      gt[6] = (__bf16)v3.x; gt[7] = (__bf16)v3.y;
    }
    gf = gt;
  }

  // feat via MFMA: C[r][m] = sum_k Q[k] * Kn[m][k]  (A = Q broadcast rows, B = gathered K)
  const int kidx = nidx[row];
  const u16* qbase = Qbf + ((size_t)bn << 8) + (hs << 5);
  const u16* kbase = Kbf + (((size_t)b << 12) + (size_t)kidx) * 256 + (hs << 5);
  const bf16x8 aq0 = *(const bf16x8*)(qbase + hf * 8);        // Q[8hf+e], k-step 0
  const bf16x8 aq1 = *(const bf16x8*)(qbase + 16 + hf * 8);   // Q[16+8hf+e], k-step 1
  const bf16x8 bk0 = *(const bf16x8*)(kbase + hf * 8);        // Kn[m][8hf+e]
  const bf16x8 bk1 = *(const bf16x8*)(kbase + 16 + hf * 8);

  const f32x16 z = {};
  f32x16 fa = __builtin_amdgcn_mfma_f32_32x32x16_bf16(aq0, bk0, z, 0, 0, 0);
  fa = __builtin_amdgcn_mfma_f32_32x32x16_bf16(aq1, bk1, fa, 0, 0, 0);
  const float feat = fa[0] * 0.17677669529663687f;   // col = m, any row reg

  // MLP layer 0
  f32x16 acc = __builtin_amdgcn_mfma_f32_32x32x16_bf16(a0, gf, z, 0, 0, 0);
  bf16x8 h0b;
  #pragma unroll
  for (int e = 0; e < 8; e++) h0b[e] = (__bf16)silu_f(acc[e] + bj0[e]);

  // MLP layer 1 + W2 contraction
  acc = __builtin_amdgcn_mfma_f32_32x32x16_bf16(a1, h0b, z, 0, 0, 0);
  float part = 0.f;
  #pragma unroll
  for (int e = 0; e < 8; e++) part += silu_f(acc[e] + bj1[e]) * wj[e];

  // cross-half combine + final
  float osum = part + __shfl_xor(part, 32, 64);
  float res = feat + silu_f(osum + b2s);

  if (hf == 0) lout[m * 8 + h] = res;
  __syncthreads();
  if (t < 64) {
    float4 v = ((const float4*)lout)[t];
    ((float4*)(out + ((size_t)bn << 8)))[t] = v;
  }
}

extern "C" void kernel_launch(void* const* d_in, const int* in_sizes, int n_in,
                              void* d_out, int out_size, void* d_ws, size_t ws_size,
                              hipStream_t stream) {
  const float* g_in = (const float*)d_in[0];
  // d_in[1] = nbhd_mask: unused by the reference
  const float* kf   = (const float*)d_in[2];
  const float* qf   = (const float*)d_in[3];
  const int*   idx  = (const int*)d_in[4];
  const float* Wk   = (const float*)d_in[5];
  const float* bk   = (const float*)d_in[6];
  const float* Wq   = (const float*)d_in[7];
  const float* bq   = (const float*)d_in[8];
  const float* W0   = (const float*)d_in[9];
  const float* b0   = (const float*)d_in[10];
  const float* W1   = (const float*)d_in[11];
  const float* b1   = (const float*)d_in[12];
  const float* W2   = (const float*)d_in[13];
  const float* b2   = (const float*)d_in[14];

  char* ws = (char*)d_ws;
  u16*   Wkt = (u16*)(ws);                     // 128 KB
  u16*   Wqt = (u16*)(ws + 131072);            // 128 KB
  u16*   W0A = (u16*)(ws + 262144);            // 8 KB
  u16*   W1A = (u16*)(ws + 270336);            // 8 KB
  float* BT2 = (float*)(ws + 278528);          // 48 KB
  u16*   Kbf = (u16*)(ws + 524288);            // 4 MB
  u16*   Qbf = (u16*)(ws + 524288 + 4194304);  // 4 MB
  u16*   G2  = (u16*)(ws + 524288 + 8388608);  // 8.39 MB (optional)

  const int useG2 = (ws_size >= (size_t)17408 * 1024) ? 1 : 0;

  prep_all<<<1089, 512, 0, stream>>>(g_in, Wk, Wq, W0, W1, b0, b1, W2,
                                     Wkt, Wqt, W0A, W1A, BT2, G2, useG2);
  gemm_proj<<<dim3(64, 2, 2), 256, 0, stream>>>(kf, qf, Wkt, Wqt, bk, bq, Kbf, Qbf);
  if (useG2)
    fused_main<1><<<8192, 512, 0, stream>>>(Kbf, Qbf, idx, g_in, W0A, W1A, BT2, b2,
                                            G2, (float*)d_out);
  else
    fused_main<0><<<8192, 512, 0, stream>>>(Kbf, Qbf, idx, g_in, W0A, W1A, BT2, b2,
                                            G2, (float*)d_out);
}